// Round 21
// baseline (234.018 us; speedup 1.0000x reference)
//
#include <hip/hip_runtime.h>
#include <math.h>

#define H_DIM 7168
#define N_EXP 256
#define N_GRP 8
#define G_SZ  32
#define TOPK_G 4
#define TOPK   8
#define BM 128
#define BK 32
#define S_TOK 16384
#define NTILES (H_DIM / BK)          // 224 total
#define NSPLIT 4
#define NQ     (NTILES / NSPLIT)     // 56 per K-quarter
#define ITILES 2                     // k-tiles per barrier interval
#define NINT   (NQ / ITILES)         // 28 intervals
#define TILE_W_BYTES 32768           // per k-tile: [eq 0-3][hi nj0-3 | lo nj0-3][lane][16B]
#define TILE_A_BYTES 16384           // per k-tile: 128 rows hi[8KB] | lo[8KB]

#define SA_SCALE 256.0f              // A * 2^8   (exact pow2)
#define SW_SCALE 4096.0f             // W * 2^12  (exact pow2)
#define DESCALE  (1.0f / 1048576.0f) // 2^-20

__device__ __align__(256) char g_wimg[(size_t)NTILES * TILE_W_BYTES];        // 7.34 MB
__device__ __align__(256) float g_part[NSPLIT * (size_t)S_TOK * N_EXP];      // 67 MB

typedef __attribute__((ext_vector_type(8))) _Float16 f16x8;
typedef __attribute__((ext_vector_type(4))) float f32x4;
typedef __attribute__((ext_vector_type(4))) unsigned short u16x4;
typedef __attribute__((ext_vector_type(8))) unsigned short u16x8;

__device__ inline void split2h(float x, unsigned short& h, unsigned short& l) {
    _Float16 hf = (_Float16)x;                 // RNE
    _Float16 lf = (_Float16)(x - (float)hf);   // exact residual
    h = __builtin_bit_cast(unsigned short, hf);
    l = __builtin_bit_cast(unsigned short, lf);
}

// ---- pre-kernel: fp32 W -> per-(eq,nj) fragment-contiguous fp16 hi/lo images ----
// expert e -> eq = e>>6 (owning wave column), nj = (e>>4)&3, col-in-frag = e&15
// (R15-verified layout)
__global__ __launch_bounds__(256)
void convert_w_kernel(const float* __restrict__ W) {
    int idx  = blockIdx.x * 256 + threadIdx.x;   // e*(H/8) + koct
    int e    = idx / (H_DIM / 8);
    int koct = idx - e * (H_DIM / 8);
    int k0   = koct * 8;
    int t    = k0 >> 5;
    int o    = (k0 >> 3) & 3;
    int lane = (e & 15) | (o << 4);
    int eq   = e >> 6;
    int nj   = (e >> 4) & 3;
    const float* src = W + (size_t)e * H_DIM + k0;
    unsigned short h[8], l[8];
    #pragma unroll
    for (int j = 0; j < 8; ++j)
        split2h(src[j] * SW_SCALE, h[j], l[j]);
    char* base = g_wimg + (size_t)t * TILE_W_BYTES + (eq << 13) + (nj << 10) + (lane << 4);
    *(u16x8*)(base)        = u16x8{h[0],h[1],h[2],h[3],h[4],h[5],h[6],h[7]};
    *(u16x8*)(base + 4096) = u16x8{l[0],l[1],l[2],l[3],l[4],l[5],l[6],l[7]};
}

// ---- main GEMM: split-K x4, BM=128, wave tile 64 rows x 64 experts (2M x 4E) ----
__global__ __launch_bounds__(512, 2)
void moe_gemm_quarter(const float* __restrict__ A)
{
    __shared__ __align__(128) char smem[2 * ITILES * TILE_A_BYTES];   // 64 KB

    const int tid   = threadIdx.x;
    const int lane  = tid & 63;
    const int wave  = tid >> 6;
    const int mh    = wave >> 2;     // row half: rows [mh*64, mh*64+64)
    const int eq    = wave & 3;      // expert quad: experts [eq*64, eq*64+64)
    // kq = b&3 constant per XCD under round-robin dispatch -> 1.84MB W
    // quarter-image is L2-resident per XCD (R18/R20-proven).
    const int b     = blockIdx.x;
    const int kq    = b & 3;
    const int brow  = (b >> 2) * BM;

    // fragment read offset (R5..R20-verified swizzle); global frag mi at mi*1024
    const int fr    = lane & 15;
    const int fkb   = (lane >> 4) << 4;
    const int fswz  = ((fr << 6) + fkb) ^ ((fr & 7) << 4);
    const int abase = (mh << 12) + fswz;     // + m*1024 (m=0..3); lo at +8192

    // A staging: thread -> rows (ar, ar+64), 4-float chunk akq
    const int ar   = tid >> 3;        // 0..63
    const int akq  = tid & 7;         // 0..7
    const int aswz = ((ar << 6) + (akq << 3)) ^ ((ar & 7) << 4);
    const float4* Ag4 = reinterpret_cast<const float4*>(
        A + (size_t)(brow + ar) * H_DIM + kq * (H_DIM / NSPLIT)) + akq;
    const size_t ROW64 = (size_t)64 * (H_DIM / 4);   // +64 rows, in float4

    f32x4 acc[4][4] = {};

    // stage two rows (r, r+64) of one k-tile (R20-proven)
    auto writeA2 = [&](const float4& v0, const float4& v1, char* ab) {
        unsigned short h0[4], l0[4], h1[4], l1[4];
        split2h(v0.x * SA_SCALE, h0[0], l0[0]); split2h(v0.y * SA_SCALE, h0[1], l0[1]);
        split2h(v0.z * SA_SCALE, h0[2], l0[2]); split2h(v0.w * SA_SCALE, h0[3], l0[3]);
        split2h(v1.x * SA_SCALE, h1[0], l1[0]); split2h(v1.y * SA_SCALE, h1[1], l1[1]);
        split2h(v1.z * SA_SCALE, h1[2], l1[2]); split2h(v1.w * SA_SCALE, h1[3], l1[3]);
        *(u16x4*)(ab + aswz)         = u16x4{h0[0], h0[1], h0[2], h0[3]};
        *(u16x4*)(ab + 4096 + aswz)  = u16x4{h1[0], h1[1], h1[2], h1[3]};
        *(u16x4*)(ab + 8192 + aswz)  = u16x4{l0[0], l0[1], l0[2], l0[3]};
        *(u16x4*)(ab + 12288 + aswz) = u16x4{l1[0], l1[1], l1[2], l1[3]};
    };

    const char* wsrc = g_wimg + (size_t)(kq * NQ) * TILE_W_BYTES
                       + (eq << 13) + (lane << 4);

    // one tile: 48 MFMA/wave. Per-acc order = HH, HL, LH (R18/R20-proven numerics).
    auto doTile = [&](int t, const char* ab) {
        const char* p = wsrc + (size_t)t * TILE_W_BYTES;
        f16x8 bh[4], bl[4];
        #pragma unroll
        for (int nj = 0; nj < 4; ++nj) {
            bh[nj] = *(const f16x8*)(p + (nj << 10));
            bl[nj] = *(const f16x8*)(p + 4096 + (nj << 10));
        }
        f16x8 ah[4];
        #pragma unroll
        for (int m = 0; m < 4; ++m)
            ah[m] = *(const f16x8*)(ab + abase + m * 1024);
        __builtin_amdgcn_s_setprio(1);
        #pragma unroll
        for (int nj = 0; nj < 4; ++nj)
            #pragma unroll
            for (int m = 0; m < 4; ++m)
                acc[m][nj] = __builtin_amdgcn_mfma_f32_16x16x32_f16(ah[m], bh[nj], acc[m][nj], 0, 0, 0);
        #pragma unroll
        for (int nj = 0; nj < 4; ++nj)
            #pragma unroll
            for (int m = 0; m < 4; ++m)
                acc[m][nj] = __builtin_amdgcn_mfma_f32_16x16x32_f16(ah[m], bl[nj], acc[m][nj], 0, 0, 0);
        __builtin_amdgcn_s_setprio(0);
        f16x8 al[4];
        #pragma unroll
        for (int m = 0; m < 4; ++m)
            al[m] = *(const f16x8*)(ab + 8192 + abase + m * 1024);
        __builtin_amdgcn_s_setprio(1);
        #pragma unroll
        for (int nj = 0; nj < 4; ++nj)
            #pragma unroll
            for (int m = 0; m < 4; ++m)
                acc[m][nj] = __builtin_amdgcn_mfma_f32_16x16x32_f16(al[m], bh[nj], acc[m][nj], 0, 0, 0);
        __builtin_amdgcn_s_setprio(0);
    };

    // ---- prologue: stage interval 0 (tiles 0,1) ----
    {
        float4 a00 = Ag4[0],      a01 = Ag4[ROW64];
        float4 a10 = Ag4[8],      a11 = Ag4[ROW64 + 8];
        writeA2(a00, a01, smem);
        writeA2(a10, a11, smem + TILE_A_BYTES);
        asm volatile("s_waitcnt lgkmcnt(0)" ::: "memory");
        __builtin_amdgcn_s_barrier();
    }

    // ---- main loop: 28 intervals x 2 tiles; direct staging at mid-interval ----
    #pragma unroll 1
    for (int i = 0; i < NINT; ++i) {
        char* cur = smem + (i & 1) * (ITILES * TILE_A_BYTES);
        char* nxt = smem + ((i + 1) & 1) * (ITILES * TILE_A_BYTES);
        const bool havenext = (i + 1 < NINT);
        const int ib = (havenext ? i + 1 : i) * ITILES;

        doTile(i * ITILES, cur);
        if (havenext) {
            float4 a00 = Ag4[(size_t)(ib + 0) * 8];
            float4 a01 = Ag4[ROW64 + (size_t)(ib + 0) * 8];
            float4 a10 = Ag4[(size_t)(ib + 1) * 8];
            float4 a11 = Ag4[ROW64 + (size_t)(ib + 1) * 8];
            writeA2(a00, a01, nxt);
            writeA2(a10, a11, nxt + TILE_A_BYTES);
        }
        doTile(i * ITILES + 1, cur + TILE_A_BYTES);
        asm volatile("s_waitcnt lgkmcnt(0)" ::: "memory");
        __builtin_amdgcn_s_barrier();
    }

    // ---- store raw fp32 partials ----
    float* pb = g_part + ((size_t)kq * S_TOK + brow) * N_EXP;
    #pragma unroll
    for (int m = 0; m < 4; ++m)
        #pragma unroll
        for (int nj = 0; nj < 4; ++nj)
            #pragma unroll
            for (int q = 0; q < 4; ++q) {
                int row = (mh << 6) + m * 16 + ((lane >> 4) << 2) + q;
                int col = (eq << 6) + nj * 16 + (lane & 15);
                pb[row * N_EXP + col] = acc[m][nj][q];
            }
}

// ---- gating: one wave per token row, 4-partial reduce (R18/R20-proven) ----
__global__ __launch_bounds__(256)
void gate_kernel(const float* __restrict__ bias, float* __restrict__ out, int S)
{
    const int lane = threadIdx.x & 63;
    const int row  = (blockIdx.x * 256 + threadIdx.x) >> 6;

    const float4 p0 = *(const float4*)(g_part + (size_t)row * N_EXP + lane * 4);
    const float4 p1 = *(const float4*)(g_part + ((size_t)S_TOK + row) * N_EXP + lane * 4);
    const float4 p2 = *(const float4*)(g_part + (2 * (size_t)S_TOK + row) * N_EXP + lane * 4);
    const float4 p3 = *(const float4*)(g_part + (3 * (size_t)S_TOK + row) * N_EXP + lane * 4);
    const float4 b4 = *(const float4*)(bias + lane * 4);

    float s[4], v[4];
    float m1 = -1e30f, m2 = -1e30f;
    {
        const float* q0 = (const float*)&p0;
        const float* q1 = (const float*)&p1;
        const float* q2 = (const float*)&p2;
        const float* q3 = (const float*)&p3;
        const float* qb = (const float*)&b4;
        #pragma unroll
        for (int j = 0; j < 4; ++j) {
            float x = (((q0[j] + q1[j]) + q2[j]) + q3[j]) * DESCALE;
            s[j] = 1.0f / (1.0f + expf(-x));
            float sb = s[j] + qb[j];
            v[j] = sb;
            if (sb > m1) { m2 = m1; m1 = sb; } else if (sb > m2) { m2 = sb; }
        }
    }
    #pragma unroll
    for (int d = 1; d < 8; d <<= 1) {
        float om1 = __shfl_xor(m1, d), om2 = __shfl_xor(m2, d);
        float hi = fmaxf(m1, om1), lo = fminf(m1, om1);
        m1 = hi;
        m2 = fmaxf(lo, fmaxf(m2, om2));
    }
    float gs = m1 + m2;
    float gsv[8];
    #pragma unroll
    for (int g = 0; g < 8; ++g) gsv[g] = __shfl(gs, g << 3);

    unsigned gmask = 0;
    #pragma unroll
    for (int t = 0; t < TOPK_G; ++t) {
        float best = -1e30f; int bg = 0;
        #pragma unroll
        for (int g = 0; g < 8; ++g) {
            bool avail = !((gmask >> g) & 1);
            if (avail && gsv[g] > best) { best = gsv[g]; bg = g; }
        }
        gmask |= 1u << bg;
    }

    const bool sel = (gmask >> (lane >> 3)) & 1;
    #pragma unroll
    for (int j = 0; j < 4; ++j) v[j] = sel ? v[j] : 0.0f;

    float wv[TOPK]; int wi[TOPK]; float wsum = 0.0f;
    #pragma unroll
    for (int t = 0; t < TOPK; ++t) {
        float bv = v[0]; int bj = 0;
        #pragma unroll
        for (int j = 1; j < 4; ++j)
            if (v[j] > bv) { bv = v[j]; bj = j; }
        int bidx = (lane << 2) | bj;
        #pragma unroll
        for (int d = 32; d >= 1; d >>= 1) {
            float ov = __shfl_xor(bv, d);
            int   oi = __shfl_xor(bidx, d);
            if (ov > bv || (ov == bv && oi < bidx)) { bv = ov; bidx = oi; }
        }
        int ol = bidx >> 2, oj = bidx & 3;
        float sl = s[0];
        if (oj == 1) sl = s[1]; else if (oj == 2) sl = s[2]; else if (oj == 3) sl = s[3];
        float sv = __shfl(sl, ol);      // UNBIASED score for the weight
        wv[t] = sv; wi[t] = bidx; wsum += sv;
        if (lane == ol) {
            if (oj == 0) v[0] = -1e30f; else if (oj == 1) v[1] = -1e30f;
            else if (oj == 2) v[2] = -1e30f; else v[3] = -1e30f;
        }
    }

    if (lane == 0) {
        float scale = 2.5f / (wsum + 1e-20f);
        #pragma unroll
        for (int t = 0; t < TOPK; ++t) {
            out[(size_t)row * TOPK + t] = wv[t] * scale;
            out[(size_t)S * TOPK + (size_t)row * TOPK + t] = (float)wi[t];
        }
    }
}

extern "C" void kernel_launch(void* const* d_in, const int* in_sizes, int n_in,
                              void* d_out, int out_size, void* d_ws, size_t ws_size,
                              hipStream_t stream) {
    const float* A    = (const float*)d_in[0];
    const float* W    = (const float*)d_in[1];
    const float* bias = (const float*)d_in[2];
    float* out = (float*)d_out;
    const int S = in_sizes[0] / H_DIM;   // 16384

    convert_w_kernel<<<dim3(N_EXP * (H_DIM / 8) / 256), 256, 0, stream>>>(W);
    moe_gemm_quarter<<<dim3(NSPLIT * S / BM), 512, 0, stream>>>(A);
    gate_kernel<<<dim3(S / 4), 256, 0, stream>>>(bias, out, S);
}

// Round 22
// 219.758 us; speedup vs baseline: 1.0649x; 1.0649x over previous
//
#include <hip/hip_runtime.h>
#include <math.h>

#define H_DIM 7168
#define N_EXP 256
#define N_GRP 8
#define G_SZ  32
#define TOPK_G 4
#define TOPK   8
#define BM 128
#define BK 32
#define S_TOK 16384
#define NTILES (H_DIM / BK)          // 224 total
#define NSPLIT 4
#define NQ     (NTILES / NSPLIT)     // 56 per K-quarter
#define ITILES 2                     // k-tiles per barrier interval
#define NINT   (NQ / ITILES)         // 28 intervals
#define TILE_W_BYTES 32768           // per k-tile: [eq 0-3][hi nj0-3 | lo nj0-3][lane][16B]
#define TILE_A_BYTES 16384           // per k-tile: 128 rows hi[8KB] | lo[8KB]

#define SA_SCALE 256.0f              // A * 2^8   (exact pow2)
#define SW_SCALE 4096.0f             // W * 2^12  (exact pow2)
#define DESCALE  (1.0f / 1048576.0f) // 2^-20

__device__ __align__(256) char g_wimg[(size_t)NTILES * TILE_W_BYTES];        // 7.34 MB
__device__ __align__(256) float g_part[NSPLIT * (size_t)S_TOK * N_EXP];      // 67 MB

typedef __attribute__((ext_vector_type(8))) _Float16 f16x8;
typedef __attribute__((ext_vector_type(4))) float f32x4;
typedef __attribute__((ext_vector_type(4))) unsigned short u16x4;
typedef __attribute__((ext_vector_type(8))) unsigned short u16x8;

__device__ inline void split2h(float x, unsigned short& h, unsigned short& l) {
    _Float16 hf = (_Float16)x;                 // RNE
    _Float16 lf = (_Float16)(x - (float)hf);   // exact residual
    h = __builtin_bit_cast(unsigned short, hf);
    l = __builtin_bit_cast(unsigned short, lf);
}

// ---- pre-kernel: fp32 W -> per-(eq,nj) fragment-contiguous fp16 hi/lo images ----
// expert e -> eq = e>>6 (owning wave), nj = (e>>4)&3, col-in-frag = e&15 (R21-verified)
__global__ __launch_bounds__(256)
void convert_w_kernel(const float* __restrict__ W) {
    int idx  = blockIdx.x * 256 + threadIdx.x;   // e*(H/8) + koct
    int e    = idx / (H_DIM / 8);
    int koct = idx - e * (H_DIM / 8);
    int k0   = koct * 8;
    int t    = k0 >> 5;
    int o    = (k0 >> 3) & 3;
    int lane = (e & 15) | (o << 4);
    int eq   = e >> 6;
    int nj   = (e >> 4) & 3;
    const float* src = W + (size_t)e * H_DIM + k0;
    unsigned short h[8], l[8];
    #pragma unroll
    for (int j = 0; j < 8; ++j)
        split2h(src[j] * SW_SCALE, h[j], l[j]);
    char* base = g_wimg + (size_t)t * TILE_W_BYTES + (eq << 13) + (nj << 10) + (lane << 4);
    *(u16x8*)(base)        = u16x8{h[0],h[1],h[2],h[3],h[4],h[5],h[6],h[7]};
    *(u16x8*)(base + 4096) = u16x8{l[0],l[1],l[2],l[3],l[4],l[5],l[6],l[7]};
}

// ---- main GEMM: split-K x4, BM=128, 4 fat waves (128 rows x 64 experts each) ----
// 256 threads, 2 blocks/CU -> 2 waves/SIMD -> 256-VGPR cap; A-LDS amplification 4x.
__global__ __launch_bounds__(256, 2)
void moe_gemm_quarter(const float* __restrict__ A)
{
    __shared__ __align__(128) char smem[2 * ITILES * TILE_A_BYTES];   // 64 KB

    const int tid   = threadIdx.x;
    const int lane  = tid & 63;
    const int wave  = tid >> 6;      // 0..3, experts [wave*64, wave*64+64)
    // kq = b&3 constant per XCD under round-robin dispatch -> 1.84MB W
    // quarter-image L2-resident per XCD (R18/R20-proven).
    const int b     = blockIdx.x;
    const int kq    = b & 3;
    const int brow  = (b >> 2) * BM;

    // fragment read offset (R5..R20-verified swizzle); frag m at m*1024, lo at +8192
    const int fr    = lane & 15;
    const int fkb   = (lane >> 4) << 4;
    const int fswz  = ((fr << 6) + fkb) ^ ((fr & 7) << 4);

    // A staging: thread -> row ar (0..127), 4-float chunks aq0..aq0+3
    const int ar   = tid >> 1;        // 0..127
    const int aq0  = (tid & 1) * 4;   // 0 or 4
    const float4* Ag4 = reinterpret_cast<const float4*>(
        A + (size_t)(brow + ar) * H_DIM + kq * (H_DIM / NSPLIT)) + aq0;

    const char* wsrc = g_wimg + (size_t)(kq * NQ) * TILE_W_BYTES
                       + (wave << 13) + (lane << 4);

    f32x4 acc[8][4] = {};

    // stage this thread's 4 chunks of one k-tile (row ar, chunks aq0..aq0+3)
    auto writeA = [&](const float4* v, char* ab) {
        #pragma unroll
        for (int j = 0; j < 4; ++j) {
            unsigned short h[4], l[4];
            split2h(v[j].x * SA_SCALE, h[0], l[0]); split2h(v[j].y * SA_SCALE, h[1], l[1]);
            split2h(v[j].z * SA_SCALE, h[2], l[2]); split2h(v[j].w * SA_SCALE, h[3], l[3]);
            int off = ((ar << 6) + ((aq0 + j) << 3)) ^ ((ar & 7) << 4);
            *(u16x4*)(ab + off)        = u16x4{h[0], h[1], h[2], h[3]};
            *(u16x4*)(ab + 8192 + off) = u16x4{l[0], l[1], l[2], l[3]};
        }
    };

    // one tile: 96 MFMA/wave. Per-acc order = HH, HL, LH (R18/R20-proven numerics).
    auto doTile = [&](int t, const char* ab) {
        const char* p = wsrc + (size_t)t * TILE_W_BYTES;
        f16x8 bh[4], bl[4];
        #pragma unroll
        for (int nj = 0; nj < 4; ++nj) {
            bh[nj] = *(const f16x8*)(p + (nj << 10));
            bl[nj] = *(const f16x8*)(p + 4096 + (nj << 10));
        }
        #pragma unroll
        for (int mb = 0; mb < 2; ++mb) {
            f16x8 ah[4];
            #pragma unroll
            for (int m = 0; m < 4; ++m)
                ah[m] = *(const f16x8*)(ab + (mb * 4 + m) * 1024 + fswz);
            __builtin_amdgcn_s_setprio(1);
            #pragma unroll
            for (int nj = 0; nj < 4; ++nj)
                #pragma unroll
                for (int m = 0; m < 4; ++m)
                    acc[mb*4+m][nj] = __builtin_amdgcn_mfma_f32_16x16x32_f16(ah[m], bh[nj], acc[mb*4+m][nj], 0, 0, 0);
            #pragma unroll
            for (int nj = 0; nj < 4; ++nj)
                #pragma unroll
                for (int m = 0; m < 4; ++m)
                    acc[mb*4+m][nj] = __builtin_amdgcn_mfma_f32_16x16x32_f16(ah[m], bl[nj], acc[mb*4+m][nj], 0, 0, 0);
            __builtin_amdgcn_s_setprio(0);
            f16x8 al[4];
            #pragma unroll
            for (int m = 0; m < 4; ++m)
                al[m] = *(const f16x8*)(ab + 8192 + (mb * 4 + m) * 1024 + fswz);
            __builtin_amdgcn_s_setprio(1);
            #pragma unroll
            for (int nj = 0; nj < 4; ++nj)
                #pragma unroll
                for (int m = 0; m < 4; ++m)
                    acc[mb*4+m][nj] = __builtin_amdgcn_mfma_f32_16x16x32_f16(al[m], bh[nj], acc[mb*4+m][nj], 0, 0, 0);
            __builtin_amdgcn_s_setprio(0);
        }
    };

    // ---- prologue: stage interval 0 (tiles 0,1) ----
    {
        float4 v0[4], v1[4];
        #pragma unroll
        for (int j = 0; j < 4; ++j) { v0[j] = Ag4[j]; v1[j] = Ag4[8 + j]; }
        writeA(v0, smem);
        writeA(v1, smem + TILE_A_BYTES);
        asm volatile("s_waitcnt lgkmcnt(0)" ::: "memory");
        __builtin_amdgcn_s_barrier();
    }

    // ---- main loop: 28 intervals x 2 tiles; direct staging at mid-interval ----
    #pragma unroll 1
    for (int i = 0; i < NINT; ++i) {
        char* cur = smem + (i & 1) * (ITILES * TILE_A_BYTES);
        char* nxt = smem + ((i + 1) & 1) * (ITILES * TILE_A_BYTES);
        const bool havenext = (i + 1 < NINT);
        const int ib = (havenext ? i + 1 : i) * ITILES;

        doTile(i * ITILES, cur);
        if (havenext) {
            float4 v0[4], v1[4];
            #pragma unroll
            for (int j = 0; j < 4; ++j) {
                v0[j] = Ag4[(size_t)(ib + 0) * 8 + j];
                v1[j] = Ag4[(size_t)(ib + 1) * 8 + j];
            }
            writeA(v0, nxt);
            writeA(v1, nxt + TILE_A_BYTES);
        }
        doTile(i * ITILES + 1, cur + TILE_A_BYTES);
        asm volatile("s_waitcnt lgkmcnt(0)" ::: "memory");
        __builtin_amdgcn_s_barrier();
    }

    // ---- store raw fp32 partials ----
    float* pb = g_part + ((size_t)kq * S_TOK + brow) * N_EXP;
    #pragma unroll
    for (int m = 0; m < 8; ++m)
        #pragma unroll
        for (int nj = 0; nj < 4; ++nj)
            #pragma unroll
            for (int q = 0; q < 4; ++q) {
                int row = m * 16 + ((lane >> 4) << 2) + q;
                int col = (wave << 6) + nj * 16 + (lane & 15);
                pb[row * N_EXP + col] = acc[m][nj][q];
            }
}

// ---- gating: one wave per token row, 4-partial reduce (R18/R20-proven) ----
__global__ __launch_bounds__(256)
void gate_kernel(const float* __restrict__ bias, float* __restrict__ out, int S)
{
    const int lane = threadIdx.x & 63;
    const int row  = (blockIdx.x * 256 + threadIdx.x) >> 6;

    const float4 p0 = *(const float4*)(g_part + (size_t)row * N_EXP + lane * 4);
    const float4 p1 = *(const float4*)(g_part + ((size_t)S_TOK + row) * N_EXP + lane * 4);
    const float4 p2 = *(const float4*)(g_part + (2 * (size_t)S_TOK + row) * N_EXP + lane * 4);
    const float4 p3 = *(const float4*)(g_part + (3 * (size_t)S_TOK + row) * N_EXP + lane * 4);
    const float4 b4 = *(const float4*)(bias + lane * 4);

    float s[4], v[4];
    float m1 = -1e30f, m2 = -1e30f;
    {
        const float* q0 = (const float*)&p0;
        const float* q1 = (const float*)&p1;
        const float* q2 = (const float*)&p2;
        const float* q3 = (const float*)&p3;
        const float* qb = (const float*)&b4;
        #pragma unroll
        for (int j = 0; j < 4; ++j) {
            float x = (((q0[j] + q1[j]) + q2[j]) + q3[j]) * DESCALE;
            s[j] = 1.0f / (1.0f + expf(-x));
            float sb = s[j] + qb[j];
            v[j] = sb;
            if (sb > m1) { m2 = m1; m1 = sb; } else if (sb > m2) { m2 = sb; }
        }
    }
    #pragma unroll
    for (int d = 1; d < 8; d <<= 1) {
        float om1 = __shfl_xor(m1, d), om2 = __shfl_xor(m2, d);
        float hi = fmaxf(m1, om1), lo = fminf(m1, om1);
        m1 = hi;
        m2 = fmaxf(lo, fmaxf(m2, om2));
    }
    float gs = m1 + m2;
    float gsv[8];
    #pragma unroll
    for (int g = 0; g < 8; ++g) gsv[g] = __shfl(gs, g << 3);

    unsigned gmask = 0;
    #pragma unroll
    for (int t = 0; t < TOPK_G; ++t) {
        float best = -1e30f; int bg = 0;
        #pragma unroll
        for (int g = 0; g < 8; ++g) {
            bool avail = !((gmask >> g) & 1);
            if (avail && gsv[g] > best) { best = gsv[g]; bg = g; }
        }
        gmask |= 1u << bg;
    }

    const bool sel = (gmask >> (lane >> 3)) & 1;
    #pragma unroll
    for (int j = 0; j < 4; ++j) v[j] = sel ? v[j] : 0.0f;

    float wv[TOPK]; int wi[TOPK]; float wsum = 0.0f;
    #pragma unroll
    for (int t = 0; t < TOPK; ++t) {
        float bv = v[0]; int bj = 0;
        #pragma unroll
        for (int j = 1; j < 4; ++j)
            if (v[j] > bv) { bv = v[j]; bj = j; }
        int bidx = (lane << 2) | bj;
        #pragma unroll
        for (int d = 32; d >= 1; d >>= 1) {
            float ov = __shfl_xor(bv, d);
            int   oi = __shfl_xor(bidx, d);
            if (ov > bv || (ov == bv && oi < bidx)) { bv = ov; bidx = oi; }
        }
        int ol = bidx >> 2, oj = bidx & 3;
        float sl = s[0];
        if (oj == 1) sl = s[1]; else if (oj == 2) sl = s[2]; else if (oj == 3) sl = s[3];
        float sv = __shfl(sl, ol);      // UNBIASED score for the weight
        wv[t] = sv; wi[t] = bidx; wsum += sv;
        if (lane == ol) {
            if (oj == 0) v[0] = -1e30f; else if (oj == 1) v[1] = -1e30f;
            else if (oj == 2) v[2] = -1e30f; else v[3] = -1e30f;
        }
    }

    if (lane == 0) {
        float scale = 2.5f / (wsum + 1e-20f);
        #pragma unroll
        for (int t = 0; t < TOPK; ++t) {
            out[(size_t)row * TOPK + t] = wv[t] * scale;
            out[(size_t)S * TOPK + (size_t)row * TOPK + t] = (float)wi[t];
        }
    }
}

extern "C" void kernel_launch(void* const* d_in, const int* in_sizes, int n_in,
                              void* d_out, int out_size, void* d_ws, size_t ws_size,
                              hipStream_t stream) {
    const float* A    = (const float*)d_in[0];
    const float* W    = (const float*)d_in[1];
    const float* bias = (const float*)d_in[2];
    float* out = (float*)d_out;
    const int S = in_sizes[0] / H_DIM;   // 16384

    convert_w_kernel<<<dim3(N_EXP * (H_DIM / 8) / 256), 256, 0, stream>>>(W);
    moe_gemm_quarter<<<dim3(NSPLIT * S / BM), 256, 0, stream>>>(A);
    gate_kernel<<<dim3(S / 4), 256, 0, stream>>>(bias, out, S);
}

// Round 23
// 208.056 us; speedup vs baseline: 1.1248x; 1.0562x over previous
//
#include <hip/hip_runtime.h>
#include <math.h>

#define H_DIM 7168
#define N_EXP 256
#define N_GRP 8
#define G_SZ  32
#define TOPK_G 4
#define TOPK   8
#define BM 128
#define BK 32
#define S_TOK 16384
#define NTILES (H_DIM / BK)          // 224 total
#define NSPLIT 4
#define NQ     (NTILES / NSPLIT)     // 56 per K-quarter
#define ITILES 2                     // k-tiles per barrier interval
#define NINT   (NQ / ITILES)         // 28 intervals
#define TILE_W_BYTES 32768           // per k-tile: [wq 0-7][frag 0-3][lane 0-63][16B]
#define TILE_A_BYTES 16384           // per k-tile: 128 rows hi[8KB] | lo[8KB]

#define SA_SCALE 256.0f              // A * 2^8   (exact pow2)
#define SW_SCALE 4096.0f             // W * 2^12  (exact pow2)
#define DESCALE  (1.0f / 1048576.0f) // 2^-20

__device__ __align__(256) char g_wimg[(size_t)NTILES * TILE_W_BYTES];        // 7.34 MB
__device__ __align__(256) float g_part[NSPLIT * (size_t)S_TOK * N_EXP];      // 67 MB

typedef __attribute__((ext_vector_type(8))) _Float16 f16x8;
typedef __attribute__((ext_vector_type(4))) float f32x4;
typedef __attribute__((ext_vector_type(4))) unsigned short u16x4;
typedef __attribute__((ext_vector_type(8))) unsigned short u16x8;

__device__ inline void split2h(float x, unsigned short& h, unsigned short& l) {
    _Float16 hf = (_Float16)x;                 // RNE
    _Float16 lf = (_Float16)(x - (float)hf);   // exact residual
    h = __builtin_bit_cast(unsigned short, hf);
    l = __builtin_bit_cast(unsigned short, lf);
}

// ---- pre-kernel: fp32 W -> per-wq fragment-contiguous fp16 hi/lo images (R12) ----
__global__ __launch_bounds__(256)
void convert_w_kernel(const float* __restrict__ W) {
    int idx  = blockIdx.x * 256 + threadIdx.x;   // e*(H/8) + koct
    int e    = idx / (H_DIM / 8);
    int koct = idx - e * (H_DIM / 8);
    int k0   = koct * 8;
    int t    = k0 >> 5;
    int o    = (k0 >> 3) & 3;
    int lane = (e & 15) | (o << 4);
    int w    = e >> 5;
    int nj   = (e >> 4) & 1;
    const float* src = W + (size_t)e * H_DIM + k0;
    unsigned short h[8], l[8];
    #pragma unroll
    for (int j = 0; j < 8; ++j)
        split2h(src[j] * SW_SCALE, h[j], l[j]);
    char* base = g_wimg + (size_t)t * TILE_W_BYTES + (w << 12) + (lane << 4);
    *(u16x8*)(base + nj * 1024)       = u16x8{h[0],h[1],h[2],h[3],h[4],h[5],h[6],h[7]};
    *(u16x8*)(base + (2 + nj) * 1024) = u16x8{l[0],l[1],l[2],l[3],l[4],l[5],l[6],l[7]};
}

// ---- main GEMM: split-K x4, BM=128 (halved W re-reads), lean register order ----
__global__ __launch_bounds__(512, 2)
void moe_gemm_quarter(const float* __restrict__ A)
{
    __shared__ __align__(128) char smem[2 * ITILES * TILE_A_BYTES];   // 64 KB

    const int tid   = threadIdx.x;
    const int lane  = tid & 63;
    const int wave  = tid >> 6;      // expert group [wave*32, wave*32+32)
    // kq = b&3 constant per XCD under round-robin dispatch -> 1.84MB W
    // quarter-image is L2-resident per XCD (R18-proven).
    const int b     = blockIdx.x;
    const int kq    = b & 3;
    const int brow  = (b >> 2) * BM;

    // fragment read offset (R5..R18-verified swizzle); frag mi at mi*1024
    const int fr   = lane & 15;
    const int fkb  = (lane >> 4) << 4;
    const int fswz = ((fr << 6) + fkb) ^ ((fr & 7) << 4);

    // A staging: thread -> rows (ar, ar+64), 4-float chunk akq
    const int ar   = tid >> 3;        // 0..63
    const int akq  = tid & 7;         // 0..7
    const int aswz = ((ar << 6) + (akq << 3)) ^ ((ar & 7) << 4);
    const float4* Ag4 = reinterpret_cast<const float4*>(
        A + (size_t)(brow + ar) * H_DIM + kq * (H_DIM / NSPLIT)) + akq;
    const size_t ROW64 = (size_t)64 * (H_DIM / 4);   // +64 rows, in float4

    f32x4 acc[8][2] = {};

    // stage two rows (r, r+64) of one k-tile
    auto writeA2 = [&](const float4& v0, const float4& v1, char* ab) {
        unsigned short h0[4], l0[4], h1[4], l1[4];
        split2h(v0.x * SA_SCALE, h0[0], l0[0]); split2h(v0.y * SA_SCALE, h0[1], l0[1]);
        split2h(v0.z * SA_SCALE, h0[2], l0[2]); split2h(v0.w * SA_SCALE, h0[3], l0[3]);
        split2h(v1.x * SA_SCALE, h1[0], l1[0]); split2h(v1.y * SA_SCALE, h1[1], l1[1]);
        split2h(v1.z * SA_SCALE, h1[2], l1[2]); split2h(v1.w * SA_SCALE, h1[3], l1[3]);
        *(u16x4*)(ab + aswz)         = u16x4{h0[0], h0[1], h0[2], h0[3]};
        *(u16x4*)(ab + 4096 + aswz)  = u16x4{h1[0], h1[1], h1[2], h1[3]};
        *(u16x4*)(ab + 8192 + aswz)  = u16x4{l0[0], l0[1], l0[2], l0[3]};
        *(u16x4*)(ab + 12288 + aswz) = u16x4{l1[0], l1[1], l1[2], l1[3]};
    };

    const char* wsrc = g_wimg + (size_t)(kq * NQ) * TILE_W_BYTES
                       + (wave << 12) + (lane << 4);

    // one tile: 48 MFMA. Per-acc order = HH, HL, LH (R18-proven numerics).
    auto doTile = [&](int t, const char* ab) {
        const char* p = wsrc + (size_t)t * TILE_W_BYTES;
        f16x8 bh0 = *(const f16x8*)(p + 0);
        f16x8 bh1 = *(const f16x8*)(p + 1024);
        f16x8 bl0 = *(const f16x8*)(p + 2048);
        f16x8 bl1 = *(const f16x8*)(p + 3072);
        #pragma unroll
        for (int mb = 0; mb < 2; ++mb) {
            f16x8 ah[4];
            #pragma unroll
            for (int m = 0; m < 4; ++m)
                ah[m] = *(const f16x8*)(ab + (mb * 4 + m) * 1024 + fswz);
            __builtin_amdgcn_s_setprio(1);
            #pragma unroll
            for (int m = 0; m < 4; ++m)
                acc[mb*4+m][0] = __builtin_amdgcn_mfma_f32_16x16x32_f16(ah[m], bh0, acc[mb*4+m][0], 0, 0, 0);
            #pragma unroll
            for (int m = 0; m < 4; ++m)
                acc[mb*4+m][1] = __builtin_amdgcn_mfma_f32_16x16x32_f16(ah[m], bh1, acc[mb*4+m][1], 0, 0, 0);
            #pragma unroll
            for (int m = 0; m < 4; ++m)
                acc[mb*4+m][0] = __builtin_amdgcn_mfma_f32_16x16x32_f16(ah[m], bl0, acc[mb*4+m][0], 0, 0, 0);
            #pragma unroll
            for (int m = 0; m < 4; ++m)
                acc[mb*4+m][1] = __builtin_amdgcn_mfma_f32_16x16x32_f16(ah[m], bl1, acc[mb*4+m][1], 0, 0, 0);
            __builtin_amdgcn_s_setprio(0);
            f16x8 al[4];
            #pragma unroll
            for (int m = 0; m < 4; ++m)
                al[m] = *(const f16x8*)(ab + 8192 + (mb * 4 + m) * 1024 + fswz);
            __builtin_amdgcn_s_setprio(1);
            #pragma unroll
            for (int m = 0; m < 4; ++m)
                acc[mb*4+m][0] = __builtin_amdgcn_mfma_f32_16x16x32_f16(al[m], bh0, acc[mb*4+m][0], 0, 0, 0);
            #pragma unroll
            for (int m = 0; m < 4; ++m)
                acc[mb*4+m][1] = __builtin_amdgcn_mfma_f32_16x16x32_f16(al[m], bh1, acc[mb*4+m][1], 0, 0, 0);
            __builtin_amdgcn_s_setprio(0);
        }
    };

    // ---- prologue: stage interval 0 (tiles 0,1) ----
    {
        float4 a00 = Ag4[0],      a01 = Ag4[ROW64];
        float4 a10 = Ag4[8],      a11 = Ag4[ROW64 + 8];
        writeA2(a00, a01, smem);
        writeA2(a10, a11, smem + TILE_A_BYTES);
        asm volatile("s_waitcnt lgkmcnt(0)" ::: "memory");
        __builtin_amdgcn_s_barrier();
    }

    // ---- main loop: 28 intervals x 2 tiles; direct staging at mid-interval ----
    #pragma unroll 1
    for (int i = 0; i < NINT; ++i) {
        char* cur = smem + (i & 1) * (ITILES * TILE_A_BYTES);
        char* nxt = smem + ((i + 1) & 1) * (ITILES * TILE_A_BYTES);
        const bool havenext = (i + 1 < NINT);
        const int ib = (havenext ? i + 1 : i) * ITILES;

        doTile(i * ITILES, cur);
        if (havenext) {
            float4 a00 = Ag4[(size_t)(ib + 0) * 8];
            float4 a01 = Ag4[ROW64 + (size_t)(ib + 0) * 8];
            float4 a10 = Ag4[(size_t)(ib + 1) * 8];
            float4 a11 = Ag4[ROW64 + (size_t)(ib + 1) * 8];
            writeA2(a00, a01, nxt);
            writeA2(a10, a11, nxt + TILE_A_BYTES);
        }
        doTile(i * ITILES + 1, cur + TILE_A_BYTES);
        asm volatile("s_waitcnt lgkmcnt(0)" ::: "memory");
        __builtin_amdgcn_s_barrier();
    }

    // ---- store raw fp32 partials ----
    float* pb = g_part + ((size_t)kq * S_TOK + brow) * N_EXP;
    #pragma unroll
    for (int mi = 0; mi < 8; ++mi)
        #pragma unroll
        for (int nj = 0; nj < 2; ++nj)
            #pragma unroll
            for (int q = 0; q < 4; ++q) {
                int row = mi * 16 + ((lane >> 4) << 2) + q;
                int col = (wave << 5) + (nj << 4) + (lane & 15);
                pb[row * N_EXP + col] = acc[mi][nj][q];
            }
}

// ---- gating: one wave per token row, 4-partial reduce (R18-proven) ----
__global__ __launch_bounds__(256)
void gate_kernel(const float* __restrict__ bias, float* __restrict__ out, int S)
{
    const int lane = threadIdx.x & 63;
    const int row  = (blockIdx.x * 256 + threadIdx.x) >> 6;

    const float4 p0 = *(const float4*)(g_part + (size_t)row * N_EXP + lane * 4);
    const float4 p1 = *(const float4*)(g_part + ((size_t)S_TOK + row) * N_EXP + lane * 4);
    const float4 p2 = *(const float4*)(g_part + (2 * (size_t)S_TOK + row) * N_EXP + lane * 4);
    const float4 p3 = *(const float4*)(g_part + (3 * (size_t)S_TOK + row) * N_EXP + lane * 4);
    const float4 b4 = *(const float4*)(bias + lane * 4);

    float s[4], v[4];
    float m1 = -1e30f, m2 = -1e30f;
    {
        const float* q0 = (const float*)&p0;
        const float* q1 = (const float*)&p1;
        const float* q2 = (const float*)&p2;
        const float* q3 = (const float*)&p3;
        const float* qb = (const float*)&b4;
        #pragma unroll
        for (int j = 0; j < 4; ++j) {
            float x = (((q0[j] + q1[j]) + q2[j]) + q3[j]) * DESCALE;
            s[j] = 1.0f / (1.0f + expf(-x));
            float sb = s[j] + qb[j];
            v[j] = sb;
            if (sb > m1) { m2 = m1; m1 = sb; } else if (sb > m2) { m2 = sb; }
        }
    }
    #pragma unroll
    for (int d = 1; d < 8; d <<= 1) {
        float om1 = __shfl_xor(m1, d), om2 = __shfl_xor(m2, d);
        float hi = fmaxf(m1, om1), lo = fminf(m1, om1);
        m1 = hi;
        m2 = fmaxf(lo, fmaxf(m2, om2));
    }
    float gs = m1 + m2;
    float gsv[8];
    #pragma unroll
    for (int g = 0; g < 8; ++g) gsv[g] = __shfl(gs, g << 3);

    unsigned gmask = 0;
    #pragma unroll
    for (int t = 0; t < TOPK_G; ++t) {
        float best = -1e30f; int bg = 0;
        #pragma unroll
        for (int g = 0; g < 8; ++g) {
            bool avail = !((gmask >> g) & 1);
            if (avail && gsv[g] > best) { best = gsv[g]; bg = g; }
        }
        gmask |= 1u << bg;
    }

    const bool sel = (gmask >> (lane >> 3)) & 1;
    #pragma unroll
    for (int j = 0; j < 4; ++j) v[j] = sel ? v[j] : 0.0f;

    float wv[TOPK]; int wi[TOPK]; float wsum = 0.0f;
    #pragma unroll
    for (int t = 0; t < TOPK; ++t) {
        float bv = v[0]; int bj = 0;
        #pragma unroll
        for (int j = 1; j < 4; ++j)
            if (v[j] > bv) { bv = v[j]; bj = j; }
        int bidx = (lane << 2) | bj;
        #pragma unroll
        for (int d = 32; d >= 1; d >>= 1) {
            float ov = __shfl_xor(bv, d);
            int   oi = __shfl_xor(bidx, d);
            if (ov > bv || (ov == bv && oi < bidx)) { bv = ov; bidx = oi; }
        }
        int ol = bidx >> 2, oj = bidx & 3;
        float sl = s[0];
        if (oj == 1) sl = s[1]; else if (oj == 2) sl = s[2]; else if (oj == 3) sl = s[3];
        float sv = __shfl(sl, ol);      // UNBIASED score for the weight
        wv[t] = sv; wi[t] = bidx; wsum += sv;
        if (lane == ol) {
            if (oj == 0) v[0] = -1e30f; else if (oj == 1) v[1] = -1e30f;
            else if (oj == 2) v[2] = -1e30f; else v[3] = -1e30f;
        }
    }

    if (lane == 0) {
        float scale = 2.5f / (wsum + 1e-20f);
        #pragma unroll
        for (int t = 0; t < TOPK; ++t) {
            out[(size_t)row * TOPK + t] = wv[t] * scale;
            out[(size_t)S * TOPK + (size_t)row * TOPK + t] = (float)wi[t];
        }
    }
}

extern "C" void kernel_launch(void* const* d_in, const int* in_sizes, int n_in,
                              void* d_out, int out_size, void* d_ws, size_t ws_size,
                              hipStream_t stream) {
    const float* A    = (const float*)d_in[0];
    const float* W    = (const float*)d_in[1];
    const float* bias = (const float*)d_in[2];
    float* out = (float*)d_out;
    const int S = in_sizes[0] / H_DIM;   // 16384

    convert_w_kernel<<<dim3(N_EXP * (H_DIM / 8) / 256), 256, 0, stream>>>(W);
    moe_gemm_quarter<<<dim3(NSPLIT * S / BM), 512, 0, stream>>>(A);
    gate_kernel<<<dim3(S / 4), 256, 0, stream>>>(bias, out, S);
}